// Round 1
// baseline (106.783 us; speedup 1.0000x reference)
//
#include <hip/hip_runtime.h>

#define DENSE 2048
#define BATCH 64
#define MAXS  1024

// Kernel A: per-batch histogram of spike_ids -> Ct in ws, plus zero d_out.
// Ct layout (float4-friendly for spmm): Ct[(k>>2)*BATCH*4 + b*4 + (k&3)] = count(b, col=k)
__global__ __launch_bounds__(256) void hist_kernel(const int* __restrict__ ids,
                                                   const int* __restrict__ ns,
                                                   float* __restrict__ Ct,
                                                   float* __restrict__ out) {
    __shared__ int cnt[DENSE];
    const int b = blockIdx.x;
    const int tid = threadIdx.x;
    #pragma unroll
    for (int k = tid; k < DENSE; k += 256) cnt[k] = 0;
    __syncthreads();
    const int n = ns[b];
    for (int i = tid; i < n; i += 256) {
        atomicAdd(&cnt[ids[b * MAXS + i]], 1);
    }
    __syncthreads();
    #pragma unroll
    for (int k = tid; k < DENSE; k += 256) {
        Ct[(size_t)((k >> 2) * BATCH + b) * 4 + (k & 3)] = (float)cnt[k];
        out[(size_t)b * DENSE + k] = 0.0f;   // zero output for spmm's atomics
    }
}

// Kernel B: out[b][j] += sum_k Ct[k][b] * W[j][k]
// lane = b (one wave covers all 64 batches); W loads are wave-uniform -> s_load.
// grid: (128 j-groups of 16, 4 k-quarters); each wave of the block takes a
// 128-wide k slice, block reduces its 4 slices in LDS, one atomicAdd set.
__global__ __launch_bounds__(256) void spmm_kernel(const float* __restrict__ W,
                                                   const float* __restrict__ Ct,
                                                   float* __restrict__ out) {
    const int tid  = threadIdx.x;
    const int lane = tid & 63;
    const int wv   = __builtin_amdgcn_readfirstlane(tid >> 6);  // wave-uniform SGPR
    const int jb   = blockIdx.x * 16;
    const int k0   = blockIdx.y * 512 + wv * 128;

    const float*  Wp = W + (size_t)jb * DENSE + k0;             // uniform base
    const float4* Cp = (const float4*)(Ct + (size_t)(k0 >> 2) * BATCH * 4) + lane;

    float acc[16];
    #pragma unroll
    for (int j = 0; j < 16; ++j) acc[j] = 0.0f;

    #pragma unroll 2
    for (int kq = 0; kq < 32; ++kq) {                           // 32 * 4 = 128 k
        const float4 cv = Cp[kq * BATCH];                       // coalesced 16B/lane
        const int kk = kq * 4;
        #pragma unroll
        for (int j = 0; j < 16; ++j) {
            const float* wr = Wp + (size_t)j * DENSE + kk;      // uniform -> s_load
            acc[j] = fmaf(wr[0], cv.x, acc[j]);
            acc[j] = fmaf(wr[1], cv.y, acc[j]);
            acc[j] = fmaf(wr[2], cv.z, acc[j]);
            acc[j] = fmaf(wr[3], cv.w, acc[j]);
        }
    }

    // Block reduction over the 4 k-slices: P[wave][b + 65*j] (65 kills conflicts)
    __shared__ float P[4][16 * 65];
    #pragma unroll
    for (int j = 0; j < 16; ++j) P[wv][lane + 65 * j] = acc[j];
    __syncthreads();

    #pragma unroll
    for (int r = 0; r < 4; ++r) {
        const int idx = r * 256 + tid;
        const int j = idx & 15;           // j fastest -> 64B-coalesced atomics
        const int b = idx >> 4;
        const int e = b + 65 * j;
        const float v = P[0][e] + P[1][e] + P[2][e] + P[3][e];
        atomicAdd(&out[(size_t)b * DENSE + jb + j], v);
    }
}

extern "C" void kernel_launch(void* const* d_in, const int* in_sizes, int n_in,
                              void* d_out, int out_size, void* d_ws, size_t ws_size,
                              hipStream_t stream) {
    const int*   ids = (const int*)d_in[0];   // [64, 1024] int32
    const int*   ns  = (const int*)d_in[1];   // [64] int32
    const float* W   = (const float*)d_in[2]; // [2048, 2048] float32
    float* out = (float*)d_out;               // [64, 2048] float32
    float* Ct  = (float*)d_ws;                // 2048*64 floats = 512 KB

    hipLaunchKernelGGL(hist_kernel, dim3(BATCH), dim3(256), 0, stream, ids, ns, Ct, out);
    hipLaunchKernelGGL(spmm_kernel, dim3(128, 4), dim3(256), 0, stream, W, Ct, out);
}

// Round 2
// 72.250 us; speedup vs baseline: 1.4780x; 1.4780x over previous
//
#include <hip/hip_runtime.h>

#define DENSE 2048
#define BATCH 64
#define MAXS  1024

typedef __attribute__((ext_vector_type(8))) __bf16 bf16x8;
typedef __attribute__((ext_vector_type(4))) float f32x4;

// ws layout: Cbf[b][k] (bf16 counts) stored in MFMA A-fragment order so spmm's
// A-frag load is one coalesced global_load_dwordx4 per lane:
//   elem (b,k) -> offset (((k>>5)*4 + (b>>4))*64 + ((b&15) | (((k>>3)&3)<<4)))*8 + (k&7)
// i.e. lane = (b&15) | (kquad<<4) holds C[b = mt*16 + (lane&15)][k = ks*32 + (lane>>4)*8 + i]
// which is exactly A[m=lane&15][k=(lane>>4)*8+i] for mfma_f32_16x16x32_bf16.

__global__ __launch_bounds__(256) void hist_kernel(const int* __restrict__ ids,
                                                   const int* __restrict__ ns,
                                                   __bf16* __restrict__ Cbf,
                                                   float* __restrict__ out) {
    __shared__ int cnt[DENSE];
    const int b = blockIdx.x;
    const int tid = threadIdx.x;
    #pragma unroll
    for (int k = tid; k < DENSE; k += 256) cnt[k] = 0;
    __syncthreads();
    const int n = ns[b];
    for (int i = tid; i < n; i += 256) {
        atomicAdd(&cnt[ids[b * MAXS + i]], 1);
    }
    __syncthreads();
    const int mt = b >> 4;
    const int bl = b & 15;
    #pragma unroll
    for (int k = tid; k < DENSE; k += 256) {
        const int lane = bl | (((k >> 3) & 3) << 4);
        const size_t off = (size_t)(((k >> 5) * 4 + mt) * 64 + lane) * 8 + (k & 7);
        Cbf[off] = (__bf16)(float)cnt[k];
        out[(size_t)b * DENSE + k] = 0.0f;   // zero output for spmm's atomics
    }
}

// spmm: out[b][j] += sum_k C[b][k] * W[j][k] via bf16 MFMA 16x16x32.
// grid (128 j-tiles of 16, 4 k-splits of 512). Block = 4 waves; wave w takes
// k-steps [ks4*16 + w*4 .. +4). B-frag (W) loaded straight from global fp32
// (16 rows x 128B contiguous per step -> fully coalesced) and cvt'd to bf16;
// A-frag (C) is a single coalesced 16B/lane load from pre-formatted ws (L2-hot).
__global__ __launch_bounds__(256) void spmm_kernel(const float* __restrict__ W,
                                                   const __bf16* __restrict__ Cbf,
                                                   float* __restrict__ out) {
    const int tid  = threadIdx.x;
    const int lane = tid & 63;
    const int wv   = tid >> 6;          // 0..3
    const int j0   = blockIdx.x * 16;   // j tile
    const int ks4  = blockIdx.y;        // 0..3 k split

    const int ln = lane & 15;           // j / m index within tile
    const int lq = lane >> 4;           // k quad 0..3

    f32x4 acc[4];
    #pragma unroll
    for (int mt = 0; mt < 4; ++mt) acc[mt] = (f32x4)0.0f;

    const int step0 = ks4 * 16 + wv * 4;
    const float* wrow = W + (size_t)(j0 + ln) * DENSE;

    #pragma unroll
    for (int s = 0; s < 4; ++s) {
        const int ks = step0 + s;
        const int kbase = ks * 32 + lq * 8;
        // B fragment: W[j0+ln][kbase .. kbase+7] fp32 -> bf16
        const f32x4 w0 = *(const f32x4*)(wrow + kbase);
        const f32x4 w1 = *(const f32x4*)(wrow + kbase + 4);
        bf16x8 bfrag;
        #pragma unroll
        for (int i = 0; i < 4; ++i) {
            bfrag[i]     = (__bf16)w0[i];
            bfrag[i + 4] = (__bf16)w1[i];
        }
        // A fragments (one per 16-row m-tile) + MFMA
        #pragma unroll
        for (int mt = 0; mt < 4; ++mt) {
            const bf16x8 afrag =
                *(const bf16x8*)(Cbf + ((size_t)(ks * 4 + mt) * 64 + lane) * 8);
            acc[mt] = __builtin_amdgcn_mfma_f32_16x16x32_bf16(afrag, bfrag, acc[mt], 0, 0, 0);
        }
    }

    // Cross-wave reduction in LDS: D[b][j] partials, 4 waves -> 1
    __shared__ float P[4 * 1024];
    #pragma unroll
    for (int mt = 0; mt < 4; ++mt) {
        #pragma unroll
        for (int r = 0; r < 4; ++r) {
            P[wv * 1024 + mt * 256 + lane * 4 + r] = acc[mt][r];
        }
    }
    __syncthreads();

    // thread t -> (jloc = t&15 fastest for coalesced atomics, bpart = t>>4)
    const int jloc  = tid & 15;
    const int bpart = tid >> 4;                       // 0..15
    const int lsrc  = ((bpart >> 2) << 4) | jloc;     // source lane
    const int r     = bpart & 3;                      // source acc reg
    #pragma unroll
    for (int mt = 0; mt < 4; ++mt) {
        const int o = mt * 256 + lsrc * 4 + r;
        const float v = P[o] + P[1024 + o] + P[2048 + o] + P[3072 + o];
        atomicAdd(&out[(size_t)(mt * 16 + bpart) * DENSE + j0 + jloc], v);
    }
}

extern "C" void kernel_launch(void* const* d_in, const int* in_sizes, int n_in,
                              void* d_out, int out_size, void* d_ws, size_t ws_size,
                              hipStream_t stream) {
    const int*   ids = (const int*)d_in[0];   // [64, 1024] int32
    const int*   ns  = (const int*)d_in[1];   // [64] int32
    const float* W   = (const float*)d_in[2]; // [2048, 2048] float32
    float*  out = (float*)d_out;              // [64, 2048] float32
    __bf16* Cbf = (__bf16*)d_ws;              // 64*2048 bf16 = 256 KB

    hipLaunchKernelGGL(hist_kernel, dim3(BATCH), dim3(256), 0, stream, ids, ns, Cbf, out);
    hipLaunchKernelGGL(spmm_kernel, dim3(128, 4), dim3(256), 0, stream, W, Cbf, out);
}